// Round 3
// baseline (39127.869 us; speedup 1.0000x reference)
//
#include <hip/hip_runtime.h>
#include <hip/hip_fp16.h>
#include <math.h>

// R10: XCD-local ESN scan — L1-coherent fast polls + bank-rotated gathers.
//  R9 post-mortem: with sc0-only *stores* (R9) AND sc0+sc1 stores (R8), the
//  sc0-only fast-path polls never saw fresh data; progress happened only on
//  the every-8th sc0+sc1 valve (step time matched that model exactly).
//  => sc0 on a LOAD does not bypass the CU's own vector L1 on gfx950: the
//  poll re-reads its own stale L1 line forever.
//  Fixes this round:
//   * fast poll round = `buffer_inv` (architected local vector-L1 invalidate;
//     the same instruction LLVM emits for acquire fences on gfx94x/gfx950)
//     followed by PLAIN global_load_dwordx4. Loads then miss L1 and read the
//     XCD-shared L2 where the sc0 (write-through) publish stores land.
//     The sc0+sc1 device-scope mirror + every-8th-round valve is kept as the
//     guaranteed-progress fallback: if buffer_inv under-delivers we get R9's
//     37ms, not a hang.
//   * bank-rotated sparse lists: at build time each lane's (val, byteoff)
//     entries are re-emitted in bank order starting at bank (lane&31), so at
//     gather step i the 64 lanes spread ~uniformly over the 32 LDS banks
//     (lanes l and l+32 share a bank = free 2-way) instead of random ~4.5-way.
//     Pure per-lane reorder of an fp32 dot sum (~1e-6 perturbation vs the
//     fp16-dominated 9.8e-4 absmax); set membership unchanged.
//  Unchanged: XCD election, 1 block/CU via 84KB LDS, tag-word parity double
//  buffer, transitive overwrite-safety chain (slot k overwritten at k+2 only
//  after every WG observed tag k).

#define T_STEPS   8192
#define WARMUP    100
#define RSIZE     2048
#define ISIZE     64
#define OUTCOLS   2112
#define GROUP     32
#define ROWS_WG   64
#define CAP       96
#define GRID      256
#define WS_BUF    64
#define WS_WORDS  (WS_BUF + 4 * RSIZE)
#define LDS_PART  8192

// build-time LDS scratch layout (overlaps the 8KB staged-h region; build
// completes before the first stage)
#define SVA_OFF   0
#define SIA_OFF   24576
#define SVB_OFF   36864
#define SIB_OFF   61440

typedef int i32x4 __attribute__((ext_vector_type(4)));

#define REP96(F) \
  F(0) F(1) F(2) F(3) F(4) F(5) F(6) F(7) \
  F(8) F(9) F(10) F(11) F(12) F(13) F(14) F(15) \
  F(16) F(17) F(18) F(19) F(20) F(21) F(22) F(23) \
  F(24) F(25) F(26) F(27) F(28) F(29) F(30) F(31) \
  F(32) F(33) F(34) F(35) F(36) F(37) F(38) F(39) \
  F(40) F(41) F(42) F(43) F(44) F(45) F(46) F(47) \
  F(48) F(49) F(50) F(51) F(52) F(53) F(54) F(55) \
  F(56) F(57) F(58) F(59) F(60) F(61) F(62) F(63) \
  F(64) F(65) F(66) F(67) F(68) F(69) F(70) F(71) \
  F(72) F(73) F(74) F(75) F(76) F(77) F(78) F(79) \
  F(80) F(81) F(82) F(83) F(84) F(85) F(86) F(87) \
  F(88) F(89) F(90) F(91) F(92) F(93) F(94) F(95)

#define REP48(F) \
  F(0) F(1) F(2) F(3) F(4) F(5) F(6) F(7) \
  F(8) F(9) F(10) F(11) F(12) F(13) F(14) F(15) \
  F(16) F(17) F(18) F(19) F(20) F(21) F(22) F(23) \
  F(24) F(25) F(26) F(27) F(28) F(29) F(30) F(31) \
  F(32) F(33) F(34) F(35) F(36) F(37) F(38) F(39) \
  F(40) F(41) F(42) F(43) F(44) F(45) F(46) F(47)

#define PAIRS(F) \
  F(0,0,1)    F(1,2,3)    F(2,4,5)    F(3,6,7)    F(4,8,9)    F(5,10,11)  F(6,12,13)  F(7,14,15) \
  F(8,16,17)  F(9,18,19)  F(10,20,21) F(11,22,23) F(12,24,25) F(13,26,27) F(14,28,29) F(15,30,31) \
  F(16,32,33) F(17,34,35) F(18,36,37) F(19,38,39) F(20,40,41) F(21,42,43) F(22,44,45) F(23,46,47) \
  F(24,48,49) F(25,50,51) F(26,52,53) F(27,54,55) F(28,56,57) F(29,58,59) F(30,60,61) F(31,62,63) \
  F(32,64,65) F(33,66,67) F(34,68,69) F(35,70,71) F(36,72,73) F(37,74,75) F(38,76,77) F(39,78,79) \
  F(40,80,81) F(41,82,83) F(42,84,85) F(43,86,87) F(44,88,89) F(45,90,91) F(46,92,93) F(47,94,95)

#define DECLV(I) float v##I = 0.0f;
#define DECLO(I) unsigned op##I = 0u;
#define SETV(I)  v##I = svB[l * CAP + (I)];
#define SETO(I)  op##I = (unsigned)siB[l * CAP + 2 * (I)] | ((unsigned)siB[l * CAP + 2 * (I) + 1] << 16);
#define PINV(I)  asm volatile("" : "+v"(v##I));
#define PINO(I)  asm volatile("" : "+v"(op##I));
#define MAC2(P, A, B) \
  if ((A) < cm) { p0 = fmaf(v##A, *(const float*)(smem + (op##P & 0xFFFFu)), p0); } \
  if ((B) < cm) { p1 = fmaf(v##B, *(const float*)(smem + (op##P >> 16)),     p1); }

static __device__ __forceinline__ float h16lo(unsigned u) {
    __half_raw hr; hr.x = (unsigned short)(u & 0xFFFFu);
    return __half2float(__half(hr));
}
static __device__ __forceinline__ unsigned short f32_to_h16(float f) {
    __half_raw hr = __half_raw(__float2half_rn(f));
    return hr.x;
}

__global__ __launch_bounds__(256) void init_ws_kernel(unsigned* ws) {
    const int t = blockIdx.x * blockDim.x + threadIdx.x;
    if (t >= WS_WORDS) return;
    unsigned v;
    if (t < WS_BUF) {
        v = (t == 8) ? 0xFFFFFFFFu : 0u;   // chosen = none; per-XCD counters = 0
    } else {
        // buffers: [L2-A][L2-B][CC-A][CC-B], each RSIZE words.
        // A-parity holds tag 0 with h_0 = fp16(0); B-parity a never-matching tag.
        v = (((t - WS_BUF) / RSIZE) & 1) ? 0xFFFF0000u : 0u;
    }
    ws[t] = v;
}

__global__ __launch_bounds__(256) void xcopy_kernel(const float* __restrict__ x,
                                                    float* __restrict__ out) {
    int t = blockIdx.x * blockDim.x + threadIdx.x;
    if (t >= (T_STEPS - WARMUP) * ISIZE) return;
    int rowo = t >> 6;
    int j    = t & 63;
    out[(size_t)rowo * OUTCOLS + RSIZE + j] = x[(size_t)(rowo + WARMUP) * ISIZE + j];
}

__global__ __launch_bounds__(256, 1) void esn_scan_kernel(
    const float* __restrict__ x,    // [8192][64]
    const float* __restrict__ Win,  // [2048][64]
    const float* __restrict__ Wh,   // [2048][2048]
    float* __restrict__ out,        // [8092][2112]
    unsigned* ws)
{
    __shared__ __align__(16) char smem[86016]; // 84KB > 80KB => exactly 1 block/CU
    __shared__ int s_rank;
    const int tid = threadIdx.x;

    // ---- election: first XCD to register 32 WGs wins ----
    if (tid == 0) {
        int xcd;
        asm volatile("s_getreg_b32 %0, hwreg(HW_REG_XCC_ID, 0, 32)" : "=s"(xcd));
        xcd &= 7;
        unsigned rank = atomicAdd(&ws[xcd], 1u);
        if (rank == GROUP - 1) atomicCAS(&ws[8], 0xFFFFFFFFu, (unsigned)xcd);
        unsigned chosen;
        do {
            chosen = __hip_atomic_load(&ws[8], __ATOMIC_RELAXED, __HIP_MEMORY_SCOPE_AGENT);
        } while (chosen == 0xFFFFFFFFu);
        s_rank = (chosen == (unsigned)xcd && rank < GROUP) ? (int)rank : -1;
    }
    __syncthreads();
    const int rank = s_rank;
    if (rank < 0) return;  // not on the chosen XCD (or a surplus WG)

    const int w = tid >> 6;          // wave 0..3 -> col strip [512w, 512w+512)
    const int l = tid & 63;          // lane -> row (rank*64 + l)
    const int row = rank * ROWS_WG + l;

    // ---- build sparse lists, then re-emit in rotated bank order ----
    float* svA = (float*)(smem + SVA_OFF);
    unsigned short* siA = (unsigned short*)(smem + SIA_OFF);
    float* svB = (float*)(smem + SVB_OFF);
    unsigned short* siB = (unsigned short*)(smem + SIB_OFF);
    int cnt = 0;
    REP96(DECLV)
    REP48(DECLO)
    const float* wrow = Wh + (size_t)row * RSIZE + w * 512;
    for (int ph = 0; ph < 4; ++ph) {
        if (w == ph) {
            // linear scan -> svA/siA
            int c = 0;
            #pragma unroll 8
            for (int j = 0; j < 512; j += 4) {
                const float4 t4 = *(const float4*)(wrow + j);
                const int cb = (w * 512 + j) * 4;   // byte offset of column in staged h
                if (t4.x != 0.0f) { if (c < CAP) { svA[l*CAP+c] = t4.x; siA[l*CAP+c] = (unsigned short)(cb     ); } ++c; }
                if (t4.y != 0.0f) { if (c < CAP) { svA[l*CAP+c] = t4.y; siA[l*CAP+c] = (unsigned short)(cb + 4 ); } ++c; }
                if (t4.z != 0.0f) { if (c < CAP) { svA[l*CAP+c] = t4.z; siA[l*CAP+c] = (unsigned short)(cb + 8 ); } ++c; }
                if (t4.w != 0.0f) { if (c < CAP) { svA[l*CAP+c] = t4.w; siA[l*CAP+c] = (unsigned short)(cb + 12); } ++c; }
            }
            cnt = (c < CAP) ? c : CAP;
            // zero the destination (tail entries must be (0.0f, off 0))
            for (int i = 0; i < CAP; ++i) { svB[l * CAP + i] = 0.0f; siB[l * CAP + i] = 0; }
            // rotated-bank emit: banks (l&31), (l&31)+1, ... each exactly once
            int c2 = 0;
            for (int bb = 0; bb < 32; ++bb) {
                const unsigned bank = (unsigned)(((l & 31) + bb) & 31);
                for (int i = 0; i < cnt; ++i) {
                    const unsigned off = siA[l * CAP + i];
                    if (((off >> 2) & 31u) == bank) {
                        svB[l * CAP + c2] = svA[l * CAP + i];
                        siB[l * CAP + c2] = (unsigned short)off;
                        ++c2;
                    }
                }
            }
            REP96(SETV)
            REP48(SETO)
        }
        __syncthreads();
    }
    REP96(PINV)
    REP48(PINO)

    // wave-uniform trip count for the unrolled MAC (zero-padded entries are benign)
    int cm = cnt;
    #pragma unroll
    for (int d = 1; d < 64; d <<= 1) { const int o = __shfl_xor(cm, d); cm = o > cm ? o : cm; }
    cm = __builtin_amdgcn_readfirstlane(cm);

    // pinned Win chunk: row, x-cols [16w, 16w+16)
    const float* wip = Win + (size_t)row * ISIZE + w * 16;
    const float4 wa4 = ((const float4*)wip)[0];
    const float4 wb4 = ((const float4*)wip)[1];
    const float4 wc4 = ((const float4*)wip)[2];
    const float4 wd4 = ((const float4*)wip)[3];
    float wi0 = wa4.x, wi1 = wa4.y, wi2  = wa4.z, wi3  = wa4.w;
    float wi4 = wb4.x, wi5 = wb4.y, wi6  = wb4.z, wi7  = wb4.w;
    float wi8 = wc4.x, wi9 = wc4.y, wi10 = wc4.z, wi11 = wc4.w;
    float wi12 = wd4.x, wi13 = wd4.y, wi14 = wd4.z, wi15 = wd4.w;
    asm volatile("" : "+v"(wi0), "+v"(wi1), "+v"(wi2), "+v"(wi3));
    asm volatile("" : "+v"(wi4), "+v"(wi5), "+v"(wi6), "+v"(wi7));
    asm volatile("" : "+v"(wi8), "+v"(wi9), "+v"(wi10), "+v"(wi11));
    asm volatile("" : "+v"(wi12), "+v"(wi13), "+v"(wi14), "+v"(wi15));

    unsigned* const bufL2 = ws + WS_BUF;              // L2-local copies (A|B)
    unsigned* const bufCC = ws + WS_BUF + 2 * RSIZE;  // device-scope mirror (A|B)
    float hcur = 0.0f;                                // live in wave-0 lanes only

    for (int k = 1; k <= T_STEPS; ++k) {
        // x chunk (wave-uniform addresses) issued before the poll
        const float* xr = x + (size_t)(k - 1) * ISIZE + w * 16;
        const float4 xa = ((const float4*)xr)[0];
        const float4 xb = ((const float4*)xr)[1];
        const float4 xc = ((const float4*)xr)[2];
        const float4 xd = ((const float4*)xr)[3];

        // ---- poll my 8 words ----
        // fast rounds: buffer_inv (local L1 invalidate) + plain loads -> L2 hit
        // every 8th round: sc0+sc1 loads of the device-scope mirror (valve)
        const int psel = ((k - 1) & 1) ? RSIZE : 0;
        const unsigned* pbL2 = bufL2 + psel + tid * 8;
        const unsigned* pbCC = bufCC + psel + tid * 8;
        const unsigned expw = (unsigned)(k - 1) << 16;
        i32x4 qa, qb;
        unsigned spin = 0;
        for (;;) {
            if ((++spin & 7u) != 0u) {
                asm volatile("buffer_inv\n\t"
                             "global_load_dwordx4 %0, %2, off\n\t"
                             "global_load_dwordx4 %1, %2, off offset:16\n\t"
                             "s_waitcnt vmcnt(0)"
                             : "=&v"(qa), "=&v"(qb) : "v"(pbL2) : "memory");
            } else {
                asm volatile("global_load_dwordx4 %0, %2, off sc0 sc1\n\t"
                             "global_load_dwordx4 %1, %2, off offset:16 sc0 sc1\n\t"
                             "s_waitcnt vmcnt(0)"
                             : "=&v"(qa), "=&v"(qb) : "v"(pbCC) : "memory");
            }
            const unsigned dd = (((unsigned)qa.x ^ expw) | ((unsigned)qa.y ^ expw) |
                                 ((unsigned)qa.z ^ expw) | ((unsigned)qa.w ^ expw) |
                                 ((unsigned)qb.x ^ expw) | ((unsigned)qb.y ^ expw) |
                                 ((unsigned)qb.z ^ expw) | ((unsigned)qb.w ^ expw));
            if (!(dd & 0xFFFF0000u)) break;
        }

        // ---- stage h -> LDS (contiguous f32, word i at byte 4*i) ----
        float4 f0, f1;
        f0.x = h16lo((unsigned)qa.x); f0.y = h16lo((unsigned)qa.y);
        f0.z = h16lo((unsigned)qa.z); f0.w = h16lo((unsigned)qa.w);
        f1.x = h16lo((unsigned)qb.x); f1.y = h16lo((unsigned)qb.y);
        f1.z = h16lo((unsigned)qb.z); f1.w = h16lo((unsigned)qb.w);
        ((float4*)smem)[tid * 2]     = f0;
        ((float4*)smem)[tid * 2 + 1] = f1;

        // Win . x partial while the stage drains
        float p0 = wi0 * xa.x;
        p0 = fmaf(wi1, xa.y, p0); p0 = fmaf(wi2,  xa.z, p0); p0 = fmaf(wi3,  xa.w, p0);
        p0 = fmaf(wi4, xb.x, p0); p0 = fmaf(wi5,  xb.y, p0); p0 = fmaf(wi6,  xb.z, p0);
        p0 = fmaf(wi7, xb.w, p0); p0 = fmaf(wi8,  xc.x, p0); p0 = fmaf(wi9,  xc.y, p0);
        p0 = fmaf(wi10, xc.z, p0); p0 = fmaf(wi11, xc.w, p0); p0 = fmaf(wi12, xd.x, p0);
        p0 = fmaf(wi13, xd.y, p0); p0 = fmaf(wi14, xd.z, p0); p0 = fmaf(wi15, xd.w, p0);
        float p1 = 0.0f;

        __syncthreads();  // A: staged h complete

        // ---- sparse MAC over my strip (2 accumulators for ILP) ----
        PAIRS(MAC2)

        ((float*)(smem + LDS_PART))[l * 4 + w] = p0 + p1;
        __syncthreads();  // B: partials complete

        // ---- wave 0: combine, activate, publish (both copies), output ----
        if (tid < 64) {
            const float4 ps = ((const float4*)(smem + LDS_PART))[tid];
            const float y = ps.x + ps.y + ps.z + ps.w;
            const float ax = fabsf(y);
            const float e  = __expf(2.0f * ax);
            float t = 1.0f - 2.0f / (e + 1.0f);
            t = copysignf(t, y);
            hcur = 0.99f * hcur + 0.01f * t;
            const unsigned word = ((unsigned)k << 16) | (unsigned)f32_to_h16(hcur);
            const int slot = ((k & 1) ? RSIZE : 0) + rank * ROWS_WG + tid;
            unsigned* qpL2 = bufL2 + slot;
            unsigned* qpCC = bufCC + slot;
            asm volatile("global_store_dword %0, %1, off sc0"     :: "v"(qpL2), "v"(word) : "memory");
            asm volatile("global_store_dword %0, %1, off sc0 sc1" :: "v"(qpCC), "v"(word) : "memory");
            if (k >= WARMUP + 1) {
                __builtin_nontemporal_store(
                    hcur, out + (size_t)(k - (WARMUP + 1)) * OUTCOLS + rank * ROWS_WG + tid);
            }
        }
        // no extra barrier: part[] reuse guarded by the publish->poll chain;
        // staged-h reuse guarded by barrier B (see R8 analysis).
    }
}

extern "C" void kernel_launch(void* const* d_in, const int* in_sizes, int n_in,
                              void* d_out, int out_size, void* d_ws, size_t ws_size,
                              hipStream_t stream) {
    const float* x   = (const float*)d_in[0];  // [8192*64]
    const float* Win = (const float*)d_in[1];  // [2048*64]
    const float* Wh  = (const float*)d_in[2];  // [2048*2048]
    float* out = (float*)d_out;                // [8092*2112]
    unsigned* ws = (unsigned*)d_ws;            // needs (64 + 4*2048) words = 33 KB

    init_ws_kernel<<<(WS_WORDS + 255) / 256, 256, 0, stream>>>(ws);

    {
        const int n = (T_STEPS - WARMUP) * ISIZE;
        xcopy_kernel<<<(n + 255) / 256, 256, 0, stream>>>(x, out);
    }

    esn_scan_kernel<<<GRID, 256, 0, stream>>>(x, Win, Wh, out, ws);
}

// Round 4
// 17355.461 us; speedup vs baseline: 2.2545x; 2.2545x over previous
//
#include <hip/hip_runtime.h>
#include <hip/hip_fp16.h>
#include <math.h>

// R11: R7's proven device-scope fabric (17.9ms) + sparse-register Wh MAC.
//  R8-R10 post-mortem: the XCD-local L2 handshake never worked (sc0 loads,
//  buffer_inv+plain loads both blind to sc0-published data; progress always
//  valve-driven at ~37-39ms). Branch abandoned. Bank-rotation of gather
//  lists REFUTED (conflicts 2.25e8 -> 2.66e8).
//  This round: byte-identical R7 communication structure (128 WGs x 16 rows,
//  8 replicas 64KB apart, agent-scope tagged b64 polls, single barrier,
//  publish lanes tid<16) with ONLY the Wh MAC replaced:
//   * dense 128-reg pinned chain (32 ds_read_b128/lane = ~1500cy LDS pipe)
//     -> sparse (val, byteoff) register lists (~13 avg / <=24 max random
//     ds_read_b32 gathers per lane, ~700-900cy incl. ~4-way conflicts).
//   * lane (r4, c4) takes the row-segment's compacted nonzeros with
//     compacted-index % 4 == c4; CAP 24/lane is guaranteed by the
//     R8-proven <=96 nonzeros per 512-col row-segment bound.
//   * zero-padded tail entries gather hs[0] * 0.0f — benign; wave-uniform
//     trip count cm (max over lanes) with uniform branches.
//  Staging drops R7's SEGPAD padding (pointless for random gathers): linear
//  hs[2048], stage pair s at word seg + s*128 + 2l. Same-wave ds ordering
//  guards stage->gather (R7-proven). Numerics: fp32 sum over the same terms,
//  reordered; fp16-h quantization dominates (absmax 9.77e-4 unchanged).

#define NWG        128
#define ROWS_PER_WG 16
#define T_STEPS    8192
#define WARMUP     100
#define RSIZE      2048
#define ISIZE      64
#define OUTCOLS    2112
#define MAXREP     8
#define REP_STRIDE_W 16384    // 64 KB / 4B between replica bases
#define CAPT       24         // sparse entries per lane (R8-proven bound /4)

#define REP24(F) \
  F(0) F(1) F(2) F(3) F(4) F(5) F(6) F(7) \
  F(8) F(9) F(10) F(11) F(12) F(13) F(14) F(15) \
  F(16) F(17) F(18) F(19) F(20) F(21) F(22) F(23)

#define REP12(F) \
  F(0) F(1) F(2) F(3) F(4) F(5) F(6) F(7) F(8) F(9) F(10) F(11)

#define PAIRS12(F) \
  F(0,0,1) F(1,2,3) F(2,4,5) F(3,6,7) F(4,8,9) F(5,10,11) \
  F(6,12,13) F(7,14,15) F(8,16,17) F(9,18,19) F(10,20,21) F(11,22,23)

#define DECLV(I) float v##I = 0.0f;
#define DECLO(I) unsigned op##I = 0u;
#define SETV(I)  v##I = sv[l * CAPT + (I)];
#define SETO(I)  op##I = (unsigned)si[l * CAPT + 2 * (I)] | ((unsigned)si[l * CAPT + 2 * (I) + 1] << 16);
#define PINV(I)  asm volatile("" : "+v"(v##I));
#define PINO(I)  asm volatile("" : "+v"(op##I));
#define MAC2(P, A, B) \
  if ((A) < cm) { p0 = fmaf(v##A, *(const float*)(hsb + (op##P & 0xFFFFu)), p0); } \
  if ((B) < cm) { p1 = fmaf(v##B, *(const float*)(hsb + (op##P >> 16)),     p1); }

static __device__ __forceinline__ float h16_to_f32(unsigned short u) {
    __half_raw hr; hr.x = u;
    return __half2float(__half(hr));
}
static __device__ __forceinline__ unsigned short f32_to_h16(float f) {
    __half_raw hr = __half_raw(__float2half_rn(f));
    return hr.x;
}

__global__ __launch_bounds__(256) void init_ws_kernel(unsigned* rep0, int nrep) {
    int t = blockIdx.x * blockDim.x + threadIdx.x;
    if (t < nrep * RSIZE) {
        int rep = t >> 11;          // RSIZE = 2048
        int idx = t & (RSIZE - 1);
        unsigned* b = rep0 + rep * REP_STRIDE_W;
        b[idx]         = 0u;           // buf0: (tag=0, h_0 = fp16 0)
        b[RSIZE + idx] = 0xFFFF0000u;  // buf1: tag 0xFFFF never matches
    }
}

__global__ __launch_bounds__(256) void xcopy_kernel(const float* __restrict__ x,
                                                    float* __restrict__ out) {
    int t = blockIdx.x * blockDim.x + threadIdx.x;
    if (t >= (T_STEPS - WARMUP) * ISIZE) return;
    int rowo = t >> 6;          // output row 0..8091
    int j    = t & 63;
    out[(size_t)rowo * OUTCOLS + RSIZE + j] = x[(size_t)(rowo + WARMUP) * ISIZE + j];
}

__global__ __launch_bounds__(256, 1) void esn_scan_kernel(
    const float* __restrict__ x,    // [8192][64]
    const float* __restrict__ Win,  // [2048][64]
    const float* __restrict__ Wh,   // [2048][2048]
    float* __restrict__ out,        // [8092][2112]
    unsigned* rep0,                 // replica 0 base; replicas at +r*REP_STRIDE_W
    int nrep, int repmask)          // nrep = pow2 in [1,8], repmask = nrep-1
{
    __shared__ __align__(16) float hs[RSIZE];     // staged h (wave w: [512w,512w+512))
    __shared__ float part[64];                    // part[r4*4 + w]
    __shared__ float sv[64 * CAPT];               // build scratch (per-wave phases)
    __shared__ unsigned short si[64 * CAPT];

    const int tid = threadIdx.x;      // 0..255
    const int wg  = blockIdx.x;       // 0..127
    const int w   = tid >> 6;         // wave 0..3 -> h segment [512w, 512w+512)
    const int l   = tid & 63;         // lane
    const int r4  = l >> 2;           // row within WG served by this lane, 0..15
    const int c4  = l & 3;            // parity class of compacted nonzeros, 0..3
    const int row = wg * ROWS_PER_WG + r4;
    const int seg = w * 512;
    const char* hsb = (const char*)hs;

    // My poll replica (fixed per WG)
    const unsigned* myrep = rep0 + (wg & repmask) * REP_STRIDE_W;

    // ---- build sparse (val, byteoff) register lists, wave-staggered ----
    int cnt = 0;
    REP24(DECLV)
    REP12(DECLO)
    const float* wrow = Wh + (size_t)row * RSIZE + seg;
    for (int ph = 0; ph < 4; ++ph) {
        if (w == ph) {
            for (int i = 0; i < CAPT; ++i) { sv[l * CAPT + i] = 0.0f; si[l * CAPT + i] = 0; }
            int c = 0, c2 = 0;
            #pragma unroll 8
            for (int j = 0; j < 512; j += 4) {
                const float4 t4 = *(const float4*)(wrow + j);
                #define TAKE(VAL, COMP) \
                    if ((VAL) != 0.0f) { \
                        if ((c & 3) == c4 && c2 < CAPT) { \
                            sv[l * CAPT + c2] = (VAL); \
                            si[l * CAPT + c2] = (unsigned short)((seg + j + (COMP)) * 4); \
                            ++c2; \
                        } \
                        ++c; \
                    }
                TAKE(t4.x, 0) TAKE(t4.y, 1) TAKE(t4.z, 2) TAKE(t4.w, 3)
                #undef TAKE
            }
            cnt = c2;
            REP24(SETV)
            REP12(SETO)
        }
        __syncthreads();
    }
    REP24(PINV)
    REP12(PINO)

    // wave-uniform trip count (zero-padded entries are benign)
    int cm = cnt;
    #pragma unroll
    for (int d = 1; d < 64; d <<= 1) { const int o = __shfl_xor(cm, d); cm = o > cm ? o : cm; }
    cm = __builtin_amdgcn_readfirstlane(cm);

    // pinned Win chunk (R7 verbatim): row, x-cols [16w + 4*c4, +4)
    float wix, wiy, wiz, wiw;
    { float4 t = *(const float4*)(Win + (size_t)row * ISIZE + w * 16 + c4 * 4);
      wix = t.x; wiy = t.y; wiz = t.z; wiw = t.w; }
    asm volatile("" : "+v"(wix), "+v"(wiy), "+v"(wiz), "+v"(wiw));

    float hcur = 0.0f;  // live only in lanes tid<16 (publish lanes)

    for (int k = 1; k <= T_STEPS; ++k) {
        // x chunk in flight during the poll
        const float4 xv = *(const float4*)(x + (size_t)(k - 1) * ISIZE + w * 16 + c4 * 4);

        // ---- poll my replica's segment: 4 coalesced b64 loads (R7 verbatim) ----
        const unsigned* bp = myrep + (((k - 1) & 1) ? RSIZE : 0) + seg;
        const unsigned long long exp64 =
            ((unsigned long long)(unsigned)(k - 1) << 16) * 0x100000001ull; // both halves
        unsigned long long q[4];
        unsigned m = 0xFu;
        while (m) {
#pragma unroll
            for (int s = 0; s < 4; ++s) {
                if (m & (1u << s)) {
                    q[s] = __hip_atomic_load(
                        (const unsigned long long*)(bp + s * 128 + 2 * l),
                        __ATOMIC_RELAXED, __HIP_MEMORY_SCOPE_AGENT);
                }
            }
#pragma unroll
            for (int s = 0; s < 4; ++s) {
                if ((m & (1u << s)) &&
                    (q[s] & 0xFFFF0000FFFF0000ull) == exp64) {
                    m &= ~(1u << s);
                }
            }
        }

        // ---- stage segment -> LDS (linear f32); same-wave ds ordering ----
#pragma unroll
        for (int s = 0; s < 4; ++s) {
            float2* d = (float2*)(hs + seg + s * 128 + 2 * l);
            float2 v;
            v.x = h16_to_f32((unsigned short)(q[s] & 0xFFFFu));
            v.y = h16_to_f32((unsigned short)((q[s] >> 32) & 0xFFFFu));
            *d = v;
        }

        // ---- Win.x partial while the stage drains ----
        float p0 = wix * xv.x + wiy * xv.y + wiz * xv.z + wiw * xv.w;
        float p1 = 0.0f;

        // ---- sparse MAC over my row's parity-class entries in this segment ----
        PAIRS12(MAC2)

        // reduce over the 4 c4 lanes (R7 verbatim)
        float p = p0 + p1;
        p += __shfl_xor(p, 1);
        p += __shfl_xor(p, 2);
        if (c4 == 0) part[r4 * 4 + w] = p;

        __syncthreads();   // the ONE barrier: guards the 64-float reduction

        // ---- publish lanes: combine, activate, publish to ALL replicas ----
        if (tid < 16) {
            const float4 ps = *(const float4*)(part + tid * 4);
            float y = ps.x + ps.y + ps.z + ps.w;
            float ax = fabsf(y);
            float e  = __expf(2.0f * ax);
            float t  = 1.0f - 2.0f / (e + 1.0f);
            t = copysignf(t, y);
            hcur = 0.99f * hcur + 0.01f * t;

            unsigned word = ((unsigned)k << 16) | (unsigned)f32_to_h16(hcur);
            const int slot = ((k & 1) ? RSIZE : 0) + wg * ROWS_PER_WG + tid;
#pragma unroll
            for (int rr = 0; rr < MAXREP; ++rr) {
                if (rr < nrep) {
                    __hip_atomic_store(rep0 + rr * REP_STRIDE_W + slot, word,
                                       __ATOMIC_RELAXED, __HIP_MEMORY_SCOPE_AGENT);
                }
            }
            if (k >= WARMUP + 1) {
                out[(size_t)(k - (WARMUP + 1)) * OUTCOLS + wg * ROWS_PER_WG + tid] = hcur;
            }
        }
        // no second barrier: hs segment is wave-private; part[] reuse protected
        // by the global publish->poll dependency chain (R7-proven).
    }
}

extern "C" void kernel_launch(void* const* d_in, const int* in_sizes, int n_in,
                              void* d_out, int out_size, void* d_ws, size_t ws_size,
                              hipStream_t stream) {
    const float* x   = (const float*)d_in[0];  // [8192*64]
    const float* Win = (const float*)d_in[1];  // [2048*64]
    const float* Wh  = (const float*)d_in[2];  // [2048*2048]
    float* out = (float*)d_out;                // [8092*2112]

    unsigned* rep0 = (unsigned*)d_ws;

    // nrep = largest power of two <= min(8, ws_size / 64KB)
    int nrep = MAXREP;
    while (nrep > 1 && (size_t)nrep * (REP_STRIDE_W * 4) > ws_size) nrep >>= 1;
    int repmask = nrep - 1;

    // init all replicas (ws is poisoned 0xAA before every timed launch)
    {
        int n = nrep * RSIZE;
        init_ws_kernel<<<(n + 255) / 256, 256, 0, stream>>>(rep0, nrep);
    }

    // x-part of the output, independent of the recurrence
    {
        int n = (T_STEPS - WARMUP) * ISIZE;
        xcopy_kernel<<<(n + 255) / 256, 256, 0, stream>>>(x, out);
    }

    // the sequential scan: 128 persistent workgroups
    esn_scan_kernel<<<NWG, 256, 0, stream>>>(x, Win, Wh, out, rep0, nrep, repmask);
}